// Round 8
// baseline (3272660.742 us; speedup 1.0000x reference)
//
#include <hip/hip_runtime.h>
#include <hip/hip_bf16.h>

// Decoder: one-hot@Wx gather -> 64-step LSTM -> Bahdanau attention softmax.
// B=32, T=64, S=64, U=512, 4U=2048, VOCAB=65.
//
// Round 8: intra-XCD L2 exchange. Protocol ledger: r4 ack+flags+clean-load
// = 4.93us/step (best); r5/r6/r7 protocol variants all worse => per-step
// cost is ~4 MALL round trips @ ~1.1us. This round shrinks the RT itself:
// all 32 LSTM wgs pinned to ONE XCD via empirical round-robin (XCD = bid%8,
// learn_hip m09), exchange via sc0-only (L2-scope) stores/loads through the
// XCD-shared L2 (~0.2us RT). L1 staleness defeated by per-step rotating
// slots (every exchange address touched once per launch => always L1-cold).
// Protocol = r4's exact proven shape. Flags memset per launch (poison can't
// fake them); stale data across replays is benign (deterministic recurrence).
// If XCD mapping/scope semantics are wrong: poll guard breaks -> VISIBLE
// absmax fail, not silent corruption.

#define NB 32
#define NT 64
#define NS 64
#define NU 512
#define N4U 2048
#define NV 65
#define NWG 32

typedef unsigned int u32;
typedef __bf16 bf16_t;
typedef bf16_t bf16x8 __attribute__((ext_vector_type(8)));
typedef float f32x4 __attribute__((ext_vector_type(4)));
typedef u32 u32x4 __attribute__((ext_vector_type(4)));

__device__ __forceinline__ unsigned short f2bf(float f) {
  u32 u = __builtin_bit_cast(u32, f);
  u += 0x7fffu + ((u >> 16) & 1u);   // round-to-nearest-even
  return (unsigned short)(u >> 16);
}
__device__ __forceinline__ float bf2f(unsigned short s) {
  return __builtin_bit_cast(float, (u32)s << 16);
}
__device__ __forceinline__ u32 pk2(float a, float b) {
  return (u32)f2bf(a) | ((u32)f2bf(b) << 16);
}
__device__ __forceinline__ float sigf(float x) { return 1.0f / (1.0f + __expf(-x)); }
__device__ __forceinline__ float tanhfast(float x) {
  float e = __expf(2.0f * x);
  return 1.0f - 2.0f / (e + 1.0f);
}

// ---------------------------------------------------------------------------
// Fused kernel, grid 256. bid%8==0 -> LSTM wg g=bid>>3 (all on XCD 0 by
// round-robin). bid%8==1 -> e2 wg (XCD 1). Others exit.
// hbuf3: [NT][32 rows][256 pairs] u32 (32KB/slot, 2MB total, L2-resident).
// flags3: [NT][32] u32, memset 0 per launch.
// ---------------------------------------------------------------------------
__global__ __launch_bounds__(256, 1)
void lstm_kernel(const int* __restrict__ labels,
                 const float* __restrict__ h0,
                 const float* __restrict__ c0,
                 const float* __restrict__ Wx,
                 const float* __restrict__ Wh,
                 const float* __restrict__ bias,
                 const float* __restrict__ enc,
                 const float* __restrict__ W2,
                 const float* __restrict__ b2,
                 u32* __restrict__ hbuf3,
                 u32* __restrict__ dec_u,   // [32*64][256] bf16-pairs
                 u32* __restrict__ flags3,
                 unsigned short* __restrict__ e2_bf)
{
  __shared__ float z_buf[NB][65];            // padded: conflict-free gate reads
  __shared__ float c_lds[NB][16];
  __shared__ float wx_lds[NV][65];           // Wx slice + bias folded, padded
  __shared__ unsigned char lab_lds[NB * NT];

  const int tid  = threadIdx.x;
  const int bid  = blockIdx.x;
  const int sel  = bid & 7;
  const int g    = bid >> 3;
  const int wave = tid >> 6, lane = tid & 63;
  const int l15  = lane & 15, l4 = lane >> 4;

  // ------------------------- e2 wgs (bid%8==1) -----------------------------
  if (sel == 1) {
    const int r0 = g * 64 + wave * 16;   // 16 rows per wave, 32 wgs cover 2048
    const int arowE = r0 + l15;
    u32x4 afragE[16];
#pragma unroll
    for (int kt = 0; kt < 16; ++kt) {
      const float* ep = enc + arowE * NU + kt * 32 + l4 * 8;
      u32x4 t;
      t.x = pk2(ep[0], ep[1]); t.y = pk2(ep[2], ep[3]);
      t.z = pk2(ep[4], ep[5]); t.w = pk2(ep[6], ep[7]);
      afragE[kt] = t;
    }
    for (int cg = 0; cg < 8; ++cg) {
      f32x4 acc[4] = {};
      for (int kt = 0; kt < 16; ++kt) {
        bf16x8 a = __builtin_bit_cast(bf16x8, afragE[kt]);
        int k0 = kt * 32 + l4 * 8;
#pragma unroll
        for (int nt = 0; nt < 4; ++nt) {
          int col = cg * 64 + nt * 16 + l15;
          union { unsigned short us[8]; bf16x8 v; } bu;
#pragma unroll
          for (int e = 0; e < 8; ++e) bu.us[e] = f2bf(W2[(k0 + e) * NU + col]);
          acc[nt] = __builtin_amdgcn_mfma_f32_16x16x32_bf16(a, bu.v, acc[nt], 0, 0, 0);
        }
      }
#pragma unroll
      for (int nt = 0; nt < 4; ++nt) {
        int col = cg * 64 + nt * 16 + l15;
        float bc = b2[col];
#pragma unroll
        for (int ri = 0; ri < 4; ++ri)
          e2_bf[(r0 + l4 * 4 + ri) * NU + col] = f2bf(acc[nt][ri] + bc);
      }
    }
    return;
  }
  if (sel != 0) return;

  // ------------------------- LSTM wgs (bid%8==0) ---------------------------
  const int wm = wave >> 1, wn = wave & 1;

  for (int i = tid; i < NV * 64; i += 256) {
    int v = i >> 6, c = i & 63;
    int j = (c >> 4) * NU + g * 16 + (c & 15);
    wx_lds[v][c] = Wx[v * N4U + j] + bias[j];
  }
  for (int i = tid; i < NB * 16; i += 256) {
    int r = i >> 4, u = i & 15;
    c_lds[r][u] = c0[r * NU + g * 16 + u];
  }
  for (int i = tid; i < NB * NT; i += 256) lab_lds[i] = (unsigned char)labels[i];

  // Wh B-fragments -> VGPRs, once (layout validated r1-r7).
  bf16x8 bfrag[16][2];
#pragma unroll
  for (int kt = 0; kt < 16; ++kt) {
#pragma unroll
    for (int nt = 0; nt < 2; ++nt) {
      int c = wn * 32 + nt * 16 + l15;
      int j = (c >> 4) * NU + g * 16 + (c & 15);
      int kb = kt * 32 + l4 * 8;
      union { unsigned short us[8]; bf16x8 v; } bu;
#pragma unroll
      for (int e = 0; e < 8; ++e) bu.us[e] = f2bf(Wh[(kb + e) * N4U + j]);
      bfrag[kt][nt] = bu.v;
    }
  }

  // A-fragments from h0: lane holds h[arow][kt*32 + l4*8 + e], e=0..7.
  const int arow = wm * 16 + l15;
  u32x4 afrag[16];
#pragma unroll
  for (int kt = 0; kt < 16; ++kt) {
    const float* hp = h0 + arow * NU + kt * 32 + l4 * 8;
    u32x4 t;
    t.x = pk2(hp[0], hp[1]); t.y = pk2(hp[2], hp[3]);
    t.z = pk2(hp[4], hp[5]); t.w = pk2(hp[6], hp[7]);
    afrag[kt] = t;
  }

  const int bb = tid >> 3;          // batch handled in update phase
  const int u2 = (tid & 7) * 2;     // unit pair
  const int ci = g * 8 + (tid & 7); // pair index in [32][256] layout

  for (int s = 0; s < NT; ++s) {
    // [B] z = h @ WhSlice  (4 chains)
    f32x4 a00 = {0.f,0.f,0.f,0.f}, a01 = a00, a10 = a00, a11 = a00;
#pragma unroll
    for (int kt = 0; kt < 16; kt += 2) {
      bf16x8 av0 = __builtin_bit_cast(bf16x8, afrag[kt]);
      bf16x8 av1 = __builtin_bit_cast(bf16x8, afrag[kt + 1]);
      a00 = __builtin_amdgcn_mfma_f32_16x16x32_bf16(av0, bfrag[kt][0],     a00, 0, 0, 0);
      a10 = __builtin_amdgcn_mfma_f32_16x16x32_bf16(av0, bfrag[kt][1],     a10, 0, 0, 0);
      a01 = __builtin_amdgcn_mfma_f32_16x16x32_bf16(av1, bfrag[kt + 1][0], a01, 0, 0, 0);
      a11 = __builtin_amdgcn_mfma_f32_16x16x32_bf16(av1, bfrag[kt + 1][1], a11, 0, 0, 0);
    }
    f32x4 acc0 = a00 + a01, acc1 = a10 + a11;

    // [C] z -> LDS
#pragma unroll
    for (int ri = 0; ri < 4; ++ri) {
      z_buf[wm * 16 + l4 * 4 + ri][wn * 32 + l15]      = acc0[ri];
      z_buf[wm * 16 + l4 * 4 + ri][wn * 32 + 16 + l15] = acc1[ri];
    }
    __syncthreads();  // [D]

    // [E] gate update (thread owns (bb, u2..u2+1))
    int lab = lab_lds[bb * NT + s];
    float hv[2];
#pragma unroll
    for (int q = 0; q < 2; ++q) {
      int u = u2 + q;
      float zi = z_buf[bb][u]      + wx_lds[lab][u];
      float zf = z_buf[bb][16 + u] + wx_lds[lab][16 + u];
      float zg = z_buf[bb][32 + u] + wx_lds[lab][32 + u];
      float zo = z_buf[bb][48 + u] + wx_lds[lab][48 + u];
      float cc = sigf(zf) * c_lds[bb][u] + sigf(zi) * tanhfast(zg);
      c_lds[bb][u] = cc;
      hv[q] = sigf(zo) * tanhfast(cc);
    }
    u32 pkv = pk2(hv[0], hv[1]);
    dec_u[(bb * NT + s) * 256 + ci] = pkv;   // history (plain store)

    if (s == NT - 1) break;

    // [F] publish own slice to slot s+1 (sc0 = L2 scope, write-through L1)
    {
      u32* sp = hbuf3 + (size_t)(s + 1) * 8192 + bb * 256 + ci;
      asm volatile("global_store_dword %0, %1, off sc0"
                   :: "v"(sp), "v"(pkv) : "memory");
    }

    // [G] own stores acked at L2; whole wg done
    asm volatile("s_waitcnt vmcnt(0)" ::: "memory");
    __syncthreads();

    // [H] arrive: flag in slot s+1 (sc0)
    if (tid == 0) {
      u32* fp = flags3 + (s + 1) * NWG + g;
      u32 one = (u32)(s + 1);
      asm volatile("global_store_dword %0, %1, off sc0"
                   :: "v"(fp), "v"(one) : "memory");
    }

    // [J] depart: poll 32 flags of slot s+1 (one coalesced 128B, L1-cold)
    {
      const u32* fp = flags3 + (s + 1) * NWG + (lane & 31);
      const u32 tg = (u32)(s + 1);
      int guard = 0;
      for (;;) {
        u32 f;
        asm volatile("global_load_dword %0, %1, off sc0\n\t"
                     "s_waitcnt vmcnt(0)"
                     : "=v"(f) : "v"(fp) : "memory");
        if (__all(f == tg)) break;
        if (++guard > 500000) break;  // anti-hang; break => visible absmax fail
        __builtin_amdgcn_s_sleep(1);
      }
    }

    // [K] 16 independent sc0 loads -> next A-fragments, waited IN-BLOCK.
    {
      const u32* ap = hbuf3 + (size_t)(s + 1) * 8192 + arow * 256 + l4 * 4;
      asm volatile(
        "global_load_dwordx4 %0, %16, off sc0\n\t"
        "global_load_dwordx4 %1, %16, off offset:64 sc0\n\t"
        "global_load_dwordx4 %2, %16, off offset:128 sc0\n\t"
        "global_load_dwordx4 %3, %16, off offset:192 sc0\n\t"
        "global_load_dwordx4 %4, %16, off offset:256 sc0\n\t"
        "global_load_dwordx4 %5, %16, off offset:320 sc0\n\t"
        "global_load_dwordx4 %6, %16, off offset:384 sc0\n\t"
        "global_load_dwordx4 %7, %16, off offset:448 sc0\n\t"
        "global_load_dwordx4 %8, %16, off offset:512 sc0\n\t"
        "global_load_dwordx4 %9, %16, off offset:576 sc0\n\t"
        "global_load_dwordx4 %10, %16, off offset:640 sc0\n\t"
        "global_load_dwordx4 %11, %16, off offset:704 sc0\n\t"
        "global_load_dwordx4 %12, %16, off offset:768 sc0\n\t"
        "global_load_dwordx4 %13, %16, off offset:832 sc0\n\t"
        "global_load_dwordx4 %14, %16, off offset:896 sc0\n\t"
        "global_load_dwordx4 %15, %16, off offset:960 sc0\n\t"
        "s_waitcnt vmcnt(0)"
        : "=&v"(afrag[0]),  "=&v"(afrag[1]),  "=&v"(afrag[2]),  "=&v"(afrag[3]),
          "=&v"(afrag[4]),  "=&v"(afrag[5]),  "=&v"(afrag[6]),  "=&v"(afrag[7]),
          "=&v"(afrag[8]),  "=&v"(afrag[9]),  "=&v"(afrag[10]), "=&v"(afrag[11]),
          "=&v"(afrag[12]), "=&v"(afrag[13]), "=&v"(afrag[14]), "=&v"(afrag[15])
        : "v"(ap)
        : "memory");
    }
  }
}

// ---------------------------------------------------------------------------
// proj (d1 only): d1 = dec@W1+b1. One wave = 16 rows x 64 cols. grid 256x256.
// ---------------------------------------------------------------------------
__global__ __launch_bounds__(256, 1)
void proj_kernel(const u32* __restrict__ dec_u,
                 const float* __restrict__ W1,
                 const float* __restrict__ b1,
                 unsigned short* __restrict__ d1_bf)
{
  const int tid = threadIdx.x;
  const int wave = tid >> 6, lane = tid & 63;
  const int l15 = lane & 15, l4 = lane >> 4;
  const int w  = blockIdx.x * 4 + wave;   // 0..1023
  const int rt = w >> 3, cg = w & 7;
  const int r0 = rt * 16;

  f32x4 acc[4] = {};
  const int arow = r0 + l15;
  for (int kt = 0; kt < 16; ++kt) {
    int k0 = kt * 32 + l4 * 8;
    bf16x8 a = __builtin_bit_cast(bf16x8,
          *reinterpret_cast<const uint4*>(dec_u + arow * 256 + (k0 >> 1)));
#pragma unroll
    for (int nt = 0; nt < 4; ++nt) {
      int col = cg * 64 + nt * 16 + l15;
      union { unsigned short us[8]; bf16x8 v; } bu;
#pragma unroll
      for (int e = 0; e < 8; ++e) bu.us[e] = f2bf(W1[(k0 + e) * NU + col]);
      acc[nt] = __builtin_amdgcn_mfma_f32_16x16x32_bf16(a, bu.v, acc[nt], 0, 0, 0);
    }
  }
#pragma unroll
  for (int nt = 0; nt < 4; ++nt) {
    int col = cg * 64 + nt * 16 + l15;
    float bc = b1[col];
#pragma unroll
    for (int ri = 0; ri < 4; ++ri) {
      int row = r0 + l4 * 4 + ri;
      d1_bf[row * NU + col] = f2bf(acc[nt][ri] + bc);
    }
  }
}

// ---------------------------------------------------------------------------
// score+softmax: one wave per (b,t); softmax over lanes; store out[b][s][t].
// ---------------------------------------------------------------------------
__global__ __launch_bounds__(256, 1)
void score_kernel(const unsigned short* __restrict__ d1_bf,
                  const unsigned short* __restrict__ e2_bf,
                  const float* __restrict__ V,
                  float* __restrict__ out)
{
  const int tid = threadIdx.x;
  const int wave = tid >> 6, lane = tid & 63;
  const int p = blockIdx.x * 4 + wave;   // 0..2047
  const int bb = p >> 6, t = p & 63;

  union { uint4 q; unsigned short us[8]; } dv;
  dv.q = *reinterpret_cast<const uint4*>(d1_bf + (bb * 64 + t) * NU + lane * 8);
  float d1f[8], Vf[8];
#pragma unroll
  for (int e = 0; e < 8; ++e) { d1f[e] = bf2f(dv.us[e]); Vf[e] = V[lane * 8 + e]; }

  float sc = 0.f;
  for (int s = 0; s < NS; ++s) {
    union { uint4 q; unsigned short us[8]; } ev;
    ev.q = *reinterpret_cast<const uint4*>(e2_bf + (bb * 64 + s) * NU + lane * 8);
    float part = 0.f;
#pragma unroll
    for (int e = 0; e < 8; ++e) part += tanhfast(d1f[e] + bf2f(ev.us[e])) * Vf[e];
#pragma unroll
    for (int o = 32; o > 0; o >>= 1) part += __shfl_xor(part, o);
    sc = (lane == s) ? part : sc;
  }
  float m = sc;
#pragma unroll
  for (int o = 32; o > 0; o >>= 1) m = fmaxf(m, __shfl_xor(m, o));
  float ex = __expf(sc - m);
  float sum = ex;
#pragma unroll
  for (int o = 32; o > 0; o >>= 1) sum += __shfl_xor(sum, o);
  out[(bb * 64 + lane) * 64 + t] = ex / sum;
}

// ---------------------------------------------------------------------------
extern "C" void kernel_launch(void* const* d_in, const int* in_sizes, int n_in,
                              void* d_out, int out_size, void* d_ws, size_t ws_size,
                              hipStream_t stream)
{
  (void)in_sizes; (void)n_in; (void)out_size;
  const int*   labels = (const int*)  d_in[0];
  const float* enc    = (const float*)d_in[1];
  const float* h0     = (const float*)d_in[2];
  const float* c0     = (const float*)d_in[3];
  const float* Wx     = (const float*)d_in[4];
  const float* Wh     = (const float*)d_in[5];
  const float* bias   = (const float*)d_in[6];
  const float* W1     = (const float*)d_in[7];
  const float* b1     = (const float*)d_in[8];
  const float* W2     = (const float*)d_in[9];
  const float* b2     = (const float*)d_in[10];
  const float* V      = (const float*)d_in[11];
  // d_in[12] = bv: additive scalar on all scores -> softmax-invariant.

  char* ws = (char*)d_ws;
  const size_t OFS_FLG = 0;                           // 8KB + pad
  const size_t OFS_HB3 = 32768;                       // 2MB slot buffer
  const size_t OFS_DEC = OFS_HB3 + (2u << 20);        // 2MB
  const size_t OFS_D1  = OFS_DEC + (2u << 20);        // 2MB
  const size_t OFS_E2  = OFS_D1  + (2u << 20);        // 2MB
  if (ws_size < OFS_E2 + (2u << 20)) return;

  u32* flags3 = (u32*)(ws + OFS_FLG);
  u32* hbuf3  = (u32*)(ws + OFS_HB3);
  u32* dec_u  = (u32*)(ws + OFS_DEC);
  unsigned short* d1_bf = (unsigned short*)(ws + OFS_D1);
  unsigned short* e2_bf = (unsigned short*)(ws + OFS_E2);
  float* out = (float*)d_out;

  hipMemsetAsync(flags3, 0, NT * NWG * 4, stream);    // poison can't fake flags
  lstm_kernel<<<dim3(256), dim3(256), 0, stream>>>(labels, h0, c0, Wx, Wh,
                                                   bias, enc, W2, b2,
                                                   hbuf3, dec_u, flags3, e2_bf);
  proj_kernel<<<dim3(256), dim3(256), 0, stream>>>(dec_u, W1, b1, d1_bf);
  score_kernel<<<dim3(512), dim3(256), 0, stream>>>(d1_bf, e2_bf, V, out);
}

// Round 9
// 3270563.086 us; speedup vs baseline: 1.0006x; 1.0006x over previous
//
#include <hip/hip_runtime.h>
#include <hip/hip_bf16.h>

// Decoder: one-hot@Wx gather -> 64-step LSTM -> Bahdanau attention softmax.
// B=32, T=64, S=64, U=512, 4U=2048, VOCAB=65.
//
// Round 9: intra-XCD L2 exchange with MEASURED placement. r8 (static bid%8
// pinning) passed-but-3.27s: sc0 stores stayed dirty in producer XCD L2;
// consumers on OTHER XCDs spun on stale lines until chance eviction => the
// static mapping didn't co-locate. Now each wg reads its real XCD via
// s_getreg(HW_REG_XCC_ID) [learn_hip m09] and self-selects: xcc==0 wgs
// ticket for the 32 LSTM roles (verifiably share XCD0's L2), xcc==1 wgs
// ticket for 32 e2 roles, rest exit. Exchange protocol = r4's proven shape
// (publish -> vmcnt ack -> flag -> poll -> one clean asm-block load), all
// sc0 (L2-scope, L1-bypass). Flags memset per launch; kernel-boundary cache
// maintenance covers graph replays. Wrong placement/semantics => guard
// break => VISIBLE absmax fail, never silent.

#define NB 32
#define NT 64
#define NS 64
#define NU 512
#define N4U 2048
#define NV 65
#define NWG 32

typedef unsigned int u32;
typedef __bf16 bf16_t;
typedef bf16_t bf16x8 __attribute__((ext_vector_type(8)));
typedef float f32x4 __attribute__((ext_vector_type(4)));
typedef u32 u32x4 __attribute__((ext_vector_type(4)));

__device__ __forceinline__ unsigned short f2bf(float f) {
  u32 u = __builtin_bit_cast(u32, f);
  u += 0x7fffu + ((u >> 16) & 1u);   // round-to-nearest-even
  return (unsigned short)(u >> 16);
}
__device__ __forceinline__ float bf2f(unsigned short s) {
  return __builtin_bit_cast(float, (u32)s << 16);
}
__device__ __forceinline__ u32 pk2(float a, float b) {
  return (u32)f2bf(a) | ((u32)f2bf(b) << 16);
}
__device__ __forceinline__ float sigf(float x) { return 1.0f / (1.0f + __expf(-x)); }
__device__ __forceinline__ float tanhfast(float x) {
  float e = __expf(2.0f * x);
  return 1.0f - 2.0f / (e + 1.0f);
}

// ---------------------------------------------------------------------------
// Fused kernel, grid 512 x 256. Role selection by XCC_ID + ticket:
//   xcc==0 & ticket<32  -> LSTM wg g=ticket  (all share XCD0 L2)
//   xcc==1 & ticket<32  -> e2 wg k=ticket
//   else exit.
// hbuf3: [NT][32 rows][256 pairs] u32 (32KB/slot, L2-resident, slot/step).
// flags3: [NT][32] u32, memset 0 per launch. ctr: 2 u32, memset 0.
// ---------------------------------------------------------------------------
__global__ __launch_bounds__(256, 1)
void lstm_kernel(const int* __restrict__ labels,
                 const float* __restrict__ h0,
                 const float* __restrict__ c0,
                 const float* __restrict__ Wx,
                 const float* __restrict__ Wh,
                 const float* __restrict__ bias,
                 const float* __restrict__ enc,
                 const float* __restrict__ W2,
                 const float* __restrict__ b2,
                 u32* __restrict__ hbuf3,
                 u32* __restrict__ dec_u,   // [32*64][256] bf16-pairs
                 u32* __restrict__ flags3,
                 u32* __restrict__ ctr,     // [2] tickets (memset 0)
                 unsigned short* __restrict__ e2_bf)
{
  __shared__ float z_buf[NB][65];            // padded: conflict-free gate reads
  __shared__ float c_lds[NB][16];
  __shared__ float wx_lds[NV][65];           // Wx slice + bias folded, padded
  __shared__ unsigned char lab_lds[NB * NT];
  __shared__ int role_s;

  const int tid  = threadIdx.x;
  const int wave = tid >> 6, lane = tid & 63;
  const int l15  = lane & 15, l4 = lane >> 4;

  // ---- role selection: real XCD via HW_REG_XCC_ID (wave-uniform) ----
  u32 xcc;
  asm volatile("s_getreg_b32 %0, hwreg(HW_REG_XCC_ID)" : "=s"(xcc));
  if (tid == 0) {
    int r = -1;
    if (xcc == 0) {
      u32 t = atomicAdd(ctr + 0, 1u);
      if (t < NWG) r = (int)t;                // LSTM role g
    } else if (xcc == 1) {
      u32 t = atomicAdd(ctr + 1, 1u);
      if (t < NWG) r = 100 + (int)t;          // e2 role k
    }
    role_s = r;
  }
  __syncthreads();
  const int role = role_s;
  if (role < 0) return;

  // ------------------------- e2 wgs (role>=100) ----------------------------
  if (role >= 100) {
    const int r0 = (role - 100) * 64 + wave * 16;   // 16 rows/wave, 2048 total
    const int arowE = r0 + l15;
    u32x4 afragE[16];
#pragma unroll
    for (int kt = 0; kt < 16; ++kt) {
      const float* ep = enc + arowE * NU + kt * 32 + l4 * 8;
      u32x4 t;
      t.x = pk2(ep[0], ep[1]); t.y = pk2(ep[2], ep[3]);
      t.z = pk2(ep[4], ep[5]); t.w = pk2(ep[6], ep[7]);
      afragE[kt] = t;
    }
    for (int cg = 0; cg < 8; ++cg) {
      f32x4 acc[4] = {};
      for (int kt = 0; kt < 16; ++kt) {
        bf16x8 a = __builtin_bit_cast(bf16x8, afragE[kt]);
        int k0 = kt * 32 + l4 * 8;
#pragma unroll
        for (int nt = 0; nt < 4; ++nt) {
          int col = cg * 64 + nt * 16 + l15;
          union { unsigned short us[8]; bf16x8 v; } bu;
#pragma unroll
          for (int e = 0; e < 8; ++e) bu.us[e] = f2bf(W2[(k0 + e) * NU + col]);
          acc[nt] = __builtin_amdgcn_mfma_f32_16x16x32_bf16(a, bu.v, acc[nt], 0, 0, 0);
        }
      }
#pragma unroll
      for (int nt = 0; nt < 4; ++nt) {
        int col = cg * 64 + nt * 16 + l15;
        float bc = b2[col];
#pragma unroll
        for (int ri = 0; ri < 4; ++ri)
          e2_bf[(r0 + l4 * 4 + ri) * NU + col] = f2bf(acc[nt][ri] + bc);
      }
    }
    return;
  }

  // ------------------------- LSTM wgs (role 0..31) -------------------------
  const int g  = role;
  const int wm = wave >> 1, wn = wave & 1;

  for (int i = tid; i < NV * 64; i += 256) {
    int v = i >> 6, c = i & 63;
    int j = (c >> 4) * NU + g * 16 + (c & 15);
    wx_lds[v][c] = Wx[v * N4U + j] + bias[j];
  }
  for (int i = tid; i < NB * 16; i += 256) {
    int r = i >> 4, u = i & 15;
    c_lds[r][u] = c0[r * NU + g * 16 + u];
  }
  for (int i = tid; i < NB * NT; i += 256) lab_lds[i] = (unsigned char)labels[i];

  // Wh B-fragments -> VGPRs, once (layout validated r1-r8).
  bf16x8 bfrag[16][2];
#pragma unroll
  for (int kt = 0; kt < 16; ++kt) {
#pragma unroll
    for (int nt = 0; nt < 2; ++nt) {
      int c = wn * 32 + nt * 16 + l15;
      int j = (c >> 4) * NU + g * 16 + (c & 15);
      int kb = kt * 32 + l4 * 8;
      union { unsigned short us[8]; bf16x8 v; } bu;
#pragma unroll
      for (int e = 0; e < 8; ++e) bu.us[e] = f2bf(Wh[(kb + e) * N4U + j]);
      bfrag[kt][nt] = bu.v;
    }
  }

  // A-fragments from h0: lane holds h[arow][kt*32 + l4*8 + e], e=0..7.
  const int arow = wm * 16 + l15;
  u32x4 afrag[16];
#pragma unroll
  for (int kt = 0; kt < 16; ++kt) {
    const float* hp = h0 + arow * NU + kt * 32 + l4 * 8;
    u32x4 t;
    t.x = pk2(hp[0], hp[1]); t.y = pk2(hp[2], hp[3]);
    t.z = pk2(hp[4], hp[5]); t.w = pk2(hp[6], hp[7]);
    afrag[kt] = t;
  }

  const int bb = tid >> 3;          // batch handled in update phase
  const int u2 = (tid & 7) * 2;     // unit pair
  const int ci = g * 8 + (tid & 7); // pair index in [32][256] layout

  for (int s = 0; s < NT; ++s) {
    // [B] z = h @ WhSlice  (4 chains)
    f32x4 a00 = {0.f,0.f,0.f,0.f}, a01 = a00, a10 = a00, a11 = a00;
#pragma unroll
    for (int kt = 0; kt < 16; kt += 2) {
      bf16x8 av0 = __builtin_bit_cast(bf16x8, afrag[kt]);
      bf16x8 av1 = __builtin_bit_cast(bf16x8, afrag[kt + 1]);
      a00 = __builtin_amdgcn_mfma_f32_16x16x32_bf16(av0, bfrag[kt][0],     a00, 0, 0, 0);
      a10 = __builtin_amdgcn_mfma_f32_16x16x32_bf16(av0, bfrag[kt][1],     a10, 0, 0, 0);
      a01 = __builtin_amdgcn_mfma_f32_16x16x32_bf16(av1, bfrag[kt + 1][0], a01, 0, 0, 0);
      a11 = __builtin_amdgcn_mfma_f32_16x16x32_bf16(av1, bfrag[kt + 1][1], a11, 0, 0, 0);
    }
    f32x4 acc0 = a00 + a01, acc1 = a10 + a11;

    // [C] z -> LDS
#pragma unroll
    for (int ri = 0; ri < 4; ++ri) {
      z_buf[wm * 16 + l4 * 4 + ri][wn * 32 + l15]      = acc0[ri];
      z_buf[wm * 16 + l4 * 4 + ri][wn * 32 + 16 + l15] = acc1[ri];
    }
    __syncthreads();  // [D]

    // [E] gate update (thread owns (bb, u2..u2+1))
    int lab = lab_lds[bb * NT + s];
    float hv[2];
#pragma unroll
    for (int q = 0; q < 2; ++q) {
      int u = u2 + q;
      float zi = z_buf[bb][u]      + wx_lds[lab][u];
      float zf = z_buf[bb][16 + u] + wx_lds[lab][16 + u];
      float zg = z_buf[bb][32 + u] + wx_lds[lab][32 + u];
      float zo = z_buf[bb][48 + u] + wx_lds[lab][48 + u];
      float cc = sigf(zf) * c_lds[bb][u] + sigf(zi) * tanhfast(zg);
      c_lds[bb][u] = cc;
      hv[q] = sigf(zo) * tanhfast(cc);
    }
    u32 pkv = pk2(hv[0], hv[1]);
    dec_u[(bb * NT + s) * 256 + ci] = pkv;   // history (plain store)

    if (s == NT - 1) break;

    // [F] publish own slice to slot s+1 (sc0 = L2-scope; shared XCD0 L2)
    {
      u32* sp = hbuf3 + (size_t)(s + 1) * 8192 + bb * 256 + ci;
      asm volatile("global_store_dword %0, %1, off sc0"
                   :: "v"(sp), "v"(pkv) : "memory");
    }

    // [G] own stores acked at L2; whole wg done
    asm volatile("s_waitcnt vmcnt(0)" ::: "memory");
    __syncthreads();

    // [H] arrive: flag in slot s+1 (sc0)
    if (tid == 0) {
      u32* fp = flags3 + (s + 1) * NWG + g;
      u32 one = (u32)(s + 1);
      asm volatile("global_store_dword %0, %1, off sc0"
                   :: "v"(fp), "v"(one) : "memory");
    }

    // [J] depart: poll 32 flags of slot s+1 (sc0 bypasses L1 -> L2-fresh)
    {
      const u32* fp = flags3 + (s + 1) * NWG + (lane & 31);
      const u32 tg = (u32)(s + 1);
      int guard = 0;
      for (;;) {
        u32 f;
        asm volatile("global_load_dword %0, %1, off sc0\n\t"
                     "s_waitcnt vmcnt(0)"
                     : "=v"(f) : "v"(fp) : "memory");
        if (__all(f == tg)) break;
        if (++guard > 500000) break;  // anti-hang; break => visible absmax fail
        __builtin_amdgcn_s_sleep(1);
      }
    }

    // [K] 16 independent sc0 loads -> next A-fragments, waited IN-BLOCK.
    {
      const u32* ap = hbuf3 + (size_t)(s + 1) * 8192 + arow * 256 + l4 * 4;
      asm volatile(
        "global_load_dwordx4 %0, %16, off sc0\n\t"
        "global_load_dwordx4 %1, %16, off offset:64 sc0\n\t"
        "global_load_dwordx4 %2, %16, off offset:128 sc0\n\t"
        "global_load_dwordx4 %3, %16, off offset:192 sc0\n\t"
        "global_load_dwordx4 %4, %16, off offset:256 sc0\n\t"
        "global_load_dwordx4 %5, %16, off offset:320 sc0\n\t"
        "global_load_dwordx4 %6, %16, off offset:384 sc0\n\t"
        "global_load_dwordx4 %7, %16, off offset:448 sc0\n\t"
        "global_load_dwordx4 %8, %16, off offset:512 sc0\n\t"
        "global_load_dwordx4 %9, %16, off offset:576 sc0\n\t"
        "global_load_dwordx4 %10, %16, off offset:640 sc0\n\t"
        "global_load_dwordx4 %11, %16, off offset:704 sc0\n\t"
        "global_load_dwordx4 %12, %16, off offset:768 sc0\n\t"
        "global_load_dwordx4 %13, %16, off offset:832 sc0\n\t"
        "global_load_dwordx4 %14, %16, off offset:896 sc0\n\t"
        "global_load_dwordx4 %15, %16, off offset:960 sc0\n\t"
        "s_waitcnt vmcnt(0)"
        : "=&v"(afrag[0]),  "=&v"(afrag[1]),  "=&v"(afrag[2]),  "=&v"(afrag[3]),
          "=&v"(afrag[4]),  "=&v"(afrag[5]),  "=&v"(afrag[6]),  "=&v"(afrag[7]),
          "=&v"(afrag[8]),  "=&v"(afrag[9]),  "=&v"(afrag[10]), "=&v"(afrag[11]),
          "=&v"(afrag[12]), "=&v"(afrag[13]), "=&v"(afrag[14]), "=&v"(afrag[15])
        : "v"(ap)
        : "memory");
    }
  }
}

// ---------------------------------------------------------------------------
// proj (d1 only): d1 = dec@W1+b1. One wave = 16 rows x 64 cols. grid 256x256.
// ---------------------------------------------------------------------------
__global__ __launch_bounds__(256, 1)
void proj_kernel(const u32* __restrict__ dec_u,
                 const float* __restrict__ W1,
                 const float* __restrict__ b1,
                 unsigned short* __restrict__ d1_bf)
{
  const int tid = threadIdx.x;
  const int wave = tid >> 6, lane = tid & 63;
  const int l15 = lane & 15, l4 = lane >> 4;
  const int w  = blockIdx.x * 4 + wave;   // 0..1023
  const int rt = w >> 3, cg = w & 7;
  const int r0 = rt * 16;

  f32x4 acc[4] = {};
  const int arow = r0 + l15;
  for (int kt = 0; kt < 16; ++kt) {
    int k0 = kt * 32 + l4 * 8;
    bf16x8 a = __builtin_bit_cast(bf16x8,
          *reinterpret_cast<const uint4*>(dec_u + arow * 256 + (k0 >> 1)));
#pragma unroll
    for (int nt = 0; nt < 4; ++nt) {
      int col = cg * 64 + nt * 16 + l15;
      union { unsigned short us[8]; bf16x8 v; } bu;
#pragma unroll
      for (int e = 0; e < 8; ++e) bu.us[e] = f2bf(W1[(k0 + e) * NU + col]);
      acc[nt] = __builtin_amdgcn_mfma_f32_16x16x32_bf16(a, bu.v, acc[nt], 0, 0, 0);
    }
  }
#pragma unroll
  for (int nt = 0; nt < 4; ++nt) {
    int col = cg * 64 + nt * 16 + l15;
    float bc = b1[col];
#pragma unroll
    for (int ri = 0; ri < 4; ++ri) {
      int row = r0 + l4 * 4 + ri;
      d1_bf[row * NU + col] = f2bf(acc[nt][ri] + bc);
    }
  }
}

// ---------------------------------------------------------------------------
// score+softmax: one wave per (b,t); softmax over lanes; store out[b][s][t].
// ---------------------------------------------------------------------------
__global__ __launch_bounds__(256, 1)
void score_kernel(const unsigned short* __restrict__ d1_bf,
                  const unsigned short* __restrict__ e2_bf,
                  const float* __restrict__ V,
                  float* __restrict__ out)
{
  const int tid = threadIdx.x;
  const int wave = tid >> 6, lane = tid & 63;
  const int p = blockIdx.x * 4 + wave;   // 0..2047
  const int bb = p >> 6, t = p & 63;

  union { uint4 q; unsigned short us[8]; } dv;
  dv.q = *reinterpret_cast<const uint4*>(d1_bf + (bb * 64 + t) * NU + lane * 8);
  float d1f[8], Vf[8];
#pragma unroll
  for (int e = 0; e < 8; ++e) { d1f[e] = bf2f(dv.us[e]); Vf[e] = V[lane * 8 + e]; }

  float sc = 0.f;
  for (int s = 0; s < NS; ++s) {
    union { uint4 q; unsigned short us[8]; } ev;
    ev.q = *reinterpret_cast<const uint4*>(e2_bf + (bb * 64 + s) * NU + lane * 8);
    float part = 0.f;
#pragma unroll
    for (int e = 0; e < 8; ++e) part += tanhfast(d1f[e] + bf2f(ev.us[e])) * Vf[e];
#pragma unroll
    for (int o = 32; o > 0; o >>= 1) part += __shfl_xor(part, o);
    sc = (lane == s) ? part : sc;
  }
  float m = sc;
#pragma unroll
  for (int o = 32; o > 0; o >>= 1) m = fmaxf(m, __shfl_xor(m, o));
  float ex = __expf(sc - m);
  float sum = ex;
#pragma unroll
  for (int o = 32; o > 0; o >>= 1) sum += __shfl_xor(sum, o);
  out[(bb * 64 + lane) * 64 + t] = ex / sum;
}

// ---------------------------------------------------------------------------
extern "C" void kernel_launch(void* const* d_in, const int* in_sizes, int n_in,
                              void* d_out, int out_size, void* d_ws, size_t ws_size,
                              hipStream_t stream)
{
  (void)in_sizes; (void)n_in; (void)out_size;
  const int*   labels = (const int*)  d_in[0];
  const float* enc    = (const float*)d_in[1];
  const float* h0     = (const float*)d_in[2];
  const float* c0     = (const float*)d_in[3];
  const float* Wx     = (const float*)d_in[4];
  const float* Wh     = (const float*)d_in[5];
  const float* bias   = (const float*)d_in[6];
  const float* W1     = (const float*)d_in[7];
  const float* b1     = (const float*)d_in[8];
  const float* W2     = (const float*)d_in[9];
  const float* b2     = (const float*)d_in[10];
  const float* V      = (const float*)d_in[11];
  // d_in[12] = bv: additive scalar on all scores -> softmax-invariant.

  char* ws = (char*)d_ws;
  const size_t OFS_FLG = 0;                           // 8KB flags
  const size_t OFS_CTR = 8192;                        // 2 u32 tickets
  const size_t OFS_HB3 = 32768;                       // 2MB slot buffer
  const size_t OFS_DEC = OFS_HB3 + (2u << 20);        // 2MB
  const size_t OFS_D1  = OFS_DEC + (2u << 20);        // 2MB
  const size_t OFS_E2  = OFS_D1  + (2u << 20);        // 2MB
  if (ws_size < OFS_E2 + (2u << 20)) return;

  u32* flags3 = (u32*)(ws + OFS_FLG);
  u32* ctr    = (u32*)(ws + OFS_CTR);
  u32* hbuf3  = (u32*)(ws + OFS_HB3);
  u32* dec_u  = (u32*)(ws + OFS_DEC);
  unsigned short* d1_bf = (unsigned short*)(ws + OFS_D1);
  unsigned short* e2_bf = (unsigned short*)(ws + OFS_E2);
  float* out = (float*)d_out;

  hipMemsetAsync(ws, 0, OFS_CTR + 256, stream);       // flags + tickets
  lstm_kernel<<<dim3(512), dim3(256), 0, stream>>>(labels, h0, c0, Wx, Wh,
                                                   bias, enc, W2, b2,
                                                   hbuf3, dec_u, flags3, ctr, e2_bf);
  proj_kernel<<<dim3(256), dim3(256), 0, stream>>>(dec_u, W1, b1, d1_bf);
  score_kernel<<<dim3(512), dim3(256), 0, stream>>>(d1_bf, e2_bf, V, out);
}

// Round 10
// 384.125 us; speedup vs baseline: 8519.7836x; 8514.3227x over previous
//
#include <hip/hip_runtime.h>
#include <hip/hip_bf16.h>

// Decoder: one-hot@Wx gather -> 64-step LSTM -> Bahdanau attention softmax.
// B=32, T=64, S=64, U=512, 4U=2048, VOCAB=65.
//
// Round 10: CONSOLIDATION. r8/r9 proved sc0-only (L2-scope) exchange gives
// no timely cross-wg visibility on gfx950 (polls never succeed; guard-break
// 3.27s both with static bid%8 and measured XCC_ID placement) -> intra-XCD
// fabric refuted. Revert to the measured protocol optimum r4 (4.93us/step:
// publish sc0sc1 -> vmcnt ack -> flag -> coalesced poll -> one in-asm-block
// reload) + the one proven-free win: e2 = enc@W2+b2 fused as wgs 32..63
// (r6). proj = d1-only. Protocol ledger: r4 4.93 < r6 5.7 < r5 5.9 < r7 7.4
// us/step; floor est. ~2 MALL RTs ~= 2.2us/step.

#define NB 32
#define NT 64
#define NS 64
#define NU 512
#define N4U 2048
#define NV 65
#define NWG 32

typedef unsigned int u32;
typedef __bf16 bf16_t;
typedef bf16_t bf16x8 __attribute__((ext_vector_type(8)));
typedef float f32x4 __attribute__((ext_vector_type(4)));
typedef u32 u32x4 __attribute__((ext_vector_type(4)));

__device__ __forceinline__ unsigned short f2bf(float f) {
  u32 u = __builtin_bit_cast(u32, f);
  u += 0x7fffu + ((u >> 16) & 1u);   // round-to-nearest-even
  return (unsigned short)(u >> 16);
}
__device__ __forceinline__ float bf2f(unsigned short s) {
  return __builtin_bit_cast(float, (u32)s << 16);
}
__device__ __forceinline__ u32 pk2(float a, float b) {
  return (u32)f2bf(a) | ((u32)f2bf(b) << 16);
}
__device__ __forceinline__ float sigf(float x) { return 1.0f / (1.0f + __expf(-x)); }
__device__ __forceinline__ float tanhfast(float x) {
  float e = __expf(2.0f * x);
  return 1.0f - 2.0f / (e + 1.0f);
}

// ---------------------------------------------------------------------------
// Fused kernel, grid 64 x 256. wgs 0..31: LSTM (wg g owns h units
// [g*16,g*16+16)). wgs 32..63: e2 projection (64 rows each).
// hbuf: [2][32][256] bf16-pairs, device-scope exchange. flags: [32] epochs.
// ---------------------------------------------------------------------------
__global__ __launch_bounds__(256, 1)
void lstm_kernel(const int* __restrict__ labels,
                 const float* __restrict__ h0,
                 const float* __restrict__ c0,
                 const float* __restrict__ Wx,
                 const float* __restrict__ Wh,
                 const float* __restrict__ bias,
                 const float* __restrict__ enc,
                 const float* __restrict__ W2,
                 const float* __restrict__ b2,
                 u32* __restrict__ hbuf,    // [2][32][256] bf16-pairs
                 u32* __restrict__ dec_u,   // [32*64][256] bf16-pairs
                 u32* __restrict__ flags,   // [32] per-wg epoch (memset 0)
                 unsigned short* __restrict__ e2_bf)
{
  __shared__ float z_buf[NB][65];            // padded: conflict-free gate reads
  __shared__ float c_lds[NB][16];
  __shared__ float wx_lds[NV][65];           // Wx slice + bias folded, padded
  __shared__ unsigned char lab_lds[NB * NT]; // labels cached (values < 65)

  const int tid  = threadIdx.x;
  const int g    = blockIdx.x;
  const int wave = tid >> 6, lane = tid & 63;
  const int l15  = lane & 15, l4 = lane >> 4;

  // ------------------------- e2 wgs (32..63) -------------------------------
  if (g >= NWG) {
    const int r0 = (g - NWG) * 64 + wave * 16;   // 16 rows per wave
    const int arowE = r0 + l15;
    u32x4 afragE[16];
#pragma unroll
    for (int kt = 0; kt < 16; ++kt) {
      const float* ep = enc + arowE * NU + kt * 32 + l4 * 8;
      u32x4 t;
      t.x = pk2(ep[0], ep[1]); t.y = pk2(ep[2], ep[3]);
      t.z = pk2(ep[4], ep[5]); t.w = pk2(ep[6], ep[7]);
      afragE[kt] = t;
    }
    for (int cg = 0; cg < 8; ++cg) {
      f32x4 acc[4] = {};
      for (int kt = 0; kt < 16; ++kt) {
        bf16x8 a = __builtin_bit_cast(bf16x8, afragE[kt]);
        int k0 = kt * 32 + l4 * 8;
#pragma unroll
        for (int nt = 0; nt < 4; ++nt) {
          int col = cg * 64 + nt * 16 + l15;
          union { unsigned short us[8]; bf16x8 v; } bu;
#pragma unroll
          for (int e = 0; e < 8; ++e) bu.us[e] = f2bf(W2[(k0 + e) * NU + col]);
          acc[nt] = __builtin_amdgcn_mfma_f32_16x16x32_bf16(a, bu.v, acc[nt], 0, 0, 0);
        }
      }
#pragma unroll
      for (int nt = 0; nt < 4; ++nt) {
        int col = cg * 64 + nt * 16 + l15;
        float bc = b2[col];
#pragma unroll
        for (int ri = 0; ri < 4; ++ri)
          e2_bf[(r0 + l4 * 4 + ri) * NU + col] = f2bf(acc[nt][ri] + bc);
      }
    }
    return;
  }

  // ------------------------- LSTM wgs (0..31) ------------------------------
  const int wm = wave >> 1, wn = wave & 1;

  for (int i = tid; i < NV * 64; i += 256) {
    int v = i >> 6, c = i & 63;
    int j = (c >> 4) * NU + g * 16 + (c & 15);
    wx_lds[v][c] = Wx[v * N4U + j] + bias[j];
  }
  for (int i = tid; i < NB * 16; i += 256) {
    int r = i >> 4, u = i & 15;
    c_lds[r][u] = c0[r * NU + g * 16 + u];
  }
  for (int i = tid; i < NB * NT; i += 256) lab_lds[i] = (unsigned char)labels[i];

  // Wh B-fragments -> VGPRs, once (layout validated r1-r9).
  bf16x8 bfrag[16][2];
#pragma unroll
  for (int kt = 0; kt < 16; ++kt) {
#pragma unroll
    for (int nt = 0; nt < 2; ++nt) {
      int c = wn * 32 + nt * 16 + l15;
      int j = (c >> 4) * NU + g * 16 + (c & 15);
      int kb = kt * 32 + l4 * 8;
      union { unsigned short us[8]; bf16x8 v; } bu;
#pragma unroll
      for (int e = 0; e < 8; ++e) bu.us[e] = f2bf(Wh[(kb + e) * N4U + j]);
      bfrag[kt][nt] = bu.v;
    }
  }

  // A-fragments from h0: lane holds h[arow][kt*32 + l4*8 + e], e=0..7.
  const int arow = wm * 16 + l15;
  u32x4 afrag[16];
#pragma unroll
  for (int kt = 0; kt < 16; ++kt) {
    const float* hp = h0 + arow * NU + kt * 32 + l4 * 8;
    u32x4 t;
    t.x = pk2(hp[0], hp[1]); t.y = pk2(hp[2], hp[3]);
    t.z = pk2(hp[4], hp[5]); t.w = pk2(hp[6], hp[7]);
    afrag[kt] = t;
  }

  const int bb = tid >> 3;          // batch handled in update phase
  const int u2 = (tid & 7) * 2;     // unit pair
  const int ci = g * 8 + (tid & 7); // u32 col in [32][256] h layout

  for (int s = 0; s < NT; ++s) {
    // [B] z = h @ WhSlice  (4 chains; afrag valid: loads waited in-block)
    f32x4 a00 = {0.f,0.f,0.f,0.f}, a01 = a00, a10 = a00, a11 = a00;
#pragma unroll
    for (int kt = 0; kt < 16; kt += 2) {
      bf16x8 av0 = __builtin_bit_cast(bf16x8, afrag[kt]);
      bf16x8 av1 = __builtin_bit_cast(bf16x8, afrag[kt + 1]);
      a00 = __builtin_amdgcn_mfma_f32_16x16x32_bf16(av0, bfrag[kt][0],     a00, 0, 0, 0);
      a10 = __builtin_amdgcn_mfma_f32_16x16x32_bf16(av0, bfrag[kt][1],     a10, 0, 0, 0);
      a01 = __builtin_amdgcn_mfma_f32_16x16x32_bf16(av1, bfrag[kt + 1][0], a01, 0, 0, 0);
      a11 = __builtin_amdgcn_mfma_f32_16x16x32_bf16(av1, bfrag[kt + 1][1], a11, 0, 0, 0);
    }
    f32x4 acc0 = a00 + a01, acc1 = a10 + a11;

    // [C] z -> LDS
#pragma unroll
    for (int ri = 0; ri < 4; ++ri) {
      z_buf[wm * 16 + l4 * 4 + ri][wn * 32 + l15]      = acc0[ri];
      z_buf[wm * 16 + l4 * 4 + ri][wn * 32 + 16 + l15] = acc1[ri];
    }
    __syncthreads();  // [D]

    // [E] gate update (thread owns (bb, u2..u2+1))
    int lab = lab_lds[bb * NT + s];
    float hv[2];
#pragma unroll
    for (int q = 0; q < 2; ++q) {
      int u = u2 + q;
      float zi = z_buf[bb][u]      + wx_lds[lab][u];
      float zf = z_buf[bb][16 + u] + wx_lds[lab][16 + u];
      float zg = z_buf[bb][32 + u] + wx_lds[lab][32 + u];
      float zo = z_buf[bb][48 + u] + wx_lds[lab][48 + u];
      float cc = sigf(zf) * c_lds[bb][u] + sigf(zi) * tanhfast(zg);
      c_lds[bb][u] = cc;
      hv[q] = sigf(zo) * tanhfast(cc);
    }
    u32 pkv = pk2(hv[0], hv[1]);

    if (s == NT - 1) {                          // last h: history only
      dec_u[(bb * NT + s) * 256 + ci] = pkv;
      break;
    }

    // [F] publish own slice (device scope)
    __hip_atomic_store(hbuf + (((s + 1) & 1) << 13) + bb * 256 + ci, pkv,
                       __ATOMIC_RELAXED, __HIP_MEMORY_SCOPE_AGENT);

    // [G] own stores acked at coherence point, whole wg done
    asm volatile("s_waitcnt vmcnt(0)" ::: "memory");
    __syncthreads();   // also fences z_buf read (E) vs next write (C)

    // [H] arrive
    if (tid == 0)
      __hip_atomic_store(flags + g, (u32)(s + 1),
                         __ATOMIC_RELAXED, __HIP_MEMORY_SCOPE_AGENT);

    // [I] history store, off the fence path
    dec_u[(bb * NT + s) * 256 + ci] = pkv;

    // [J] depart: poll all 32 flags, one coalesced load per wave
    {
      const u32 target = (u32)(s + 1);
      int guard = 0;
      for (;;) {
        u32 f = target;
        if (lane < NWG)
          f = __hip_atomic_load(flags + lane, __ATOMIC_RELAXED,
                                __HIP_MEMORY_SCOPE_AGENT);
        if (__all(f >= target)) break;
        if (++guard > 300000) break;   // anti-hang; break => visible absmax fail
        __builtin_amdgcn_s_sleep(1);
      }
    }

    // [K] 16 independent bypass loads -> next A-fragments, waited IN-BLOCK.
    {
      const u32* ap = hbuf + (((s + 1) & 1) << 13) + arow * 256 + l4 * 4;
      asm volatile(
        "global_load_dwordx4 %0, %16, off sc0 sc1\n\t"
        "global_load_dwordx4 %1, %16, off offset:64 sc0 sc1\n\t"
        "global_load_dwordx4 %2, %16, off offset:128 sc0 sc1\n\t"
        "global_load_dwordx4 %3, %16, off offset:192 sc0 sc1\n\t"
        "global_load_dwordx4 %4, %16, off offset:256 sc0 sc1\n\t"
        "global_load_dwordx4 %5, %16, off offset:320 sc0 sc1\n\t"
        "global_load_dwordx4 %6, %16, off offset:384 sc0 sc1\n\t"
        "global_load_dwordx4 %7, %16, off offset:448 sc0 sc1\n\t"
        "global_load_dwordx4 %8, %16, off offset:512 sc0 sc1\n\t"
        "global_load_dwordx4 %9, %16, off offset:576 sc0 sc1\n\t"
        "global_load_dwordx4 %10, %16, off offset:640 sc0 sc1\n\t"
        "global_load_dwordx4 %11, %16, off offset:704 sc0 sc1\n\t"
        "global_load_dwordx4 %12, %16, off offset:768 sc0 sc1\n\t"
        "global_load_dwordx4 %13, %16, off offset:832 sc0 sc1\n\t"
        "global_load_dwordx4 %14, %16, off offset:896 sc0 sc1\n\t"
        "global_load_dwordx4 %15, %16, off offset:960 sc0 sc1\n\t"
        "s_waitcnt vmcnt(0)"
        : "=&v"(afrag[0]),  "=&v"(afrag[1]),  "=&v"(afrag[2]),  "=&v"(afrag[3]),
          "=&v"(afrag[4]),  "=&v"(afrag[5]),  "=&v"(afrag[6]),  "=&v"(afrag[7]),
          "=&v"(afrag[8]),  "=&v"(afrag[9]),  "=&v"(afrag[10]), "=&v"(afrag[11]),
          "=&v"(afrag[12]), "=&v"(afrag[13]), "=&v"(afrag[14]), "=&v"(afrag[15])
        : "v"(ap)
        : "memory");
    }
  }
}

// ---------------------------------------------------------------------------
// proj (d1 only): d1 = dec@W1+b1. One wave = 16 rows x 64 cols. grid 256x256.
// ---------------------------------------------------------------------------
__global__ __launch_bounds__(256, 1)
void proj_kernel(const u32* __restrict__ dec_u,
                 const float* __restrict__ W1,
                 const float* __restrict__ b1,
                 unsigned short* __restrict__ d1_bf)
{
  const int tid = threadIdx.x;
  const int wave = tid >> 6, lane = tid & 63;
  const int l15 = lane & 15, l4 = lane >> 4;
  const int w  = blockIdx.x * 4 + wave;   // 0..1023
  const int rt = w >> 3, cg = w & 7;
  const int r0 = rt * 16;

  f32x4 acc[4] = {};
  const int arow = r0 + l15;
  for (int kt = 0; kt < 16; ++kt) {
    int k0 = kt * 32 + l4 * 8;
    bf16x8 a = __builtin_bit_cast(bf16x8,
          *reinterpret_cast<const uint4*>(dec_u + arow * 256 + (k0 >> 1)));
#pragma unroll
    for (int nt = 0; nt < 4; ++nt) {
      int col = cg * 64 + nt * 16 + l15;
      union { unsigned short us[8]; bf16x8 v; } bu;
#pragma unroll
      for (int e = 0; e < 8; ++e) bu.us[e] = f2bf(W1[(k0 + e) * NU + col]);
      acc[nt] = __builtin_amdgcn_mfma_f32_16x16x32_bf16(a, bu.v, acc[nt], 0, 0, 0);
    }
  }
#pragma unroll
  for (int nt = 0; nt < 4; ++nt) {
    int col = cg * 64 + nt * 16 + l15;
    float bc = b1[col];
#pragma unroll
    for (int ri = 0; ri < 4; ++ri) {
      int row = r0 + l4 * 4 + ri;
      d1_bf[row * NU + col] = f2bf(acc[nt][ri] + bc);
    }
  }
}

// ---------------------------------------------------------------------------
// score+softmax: one wave per (b,t); softmax over lanes; store out[b][s][t].
// ---------------------------------------------------------------------------
__global__ __launch_bounds__(256, 1)
void score_kernel(const unsigned short* __restrict__ d1_bf,
                  const unsigned short* __restrict__ e2_bf,
                  const float* __restrict__ V,
                  float* __restrict__ out)
{
  const int tid = threadIdx.x;
  const int wave = tid >> 6, lane = tid & 63;
  const int p = blockIdx.x * 4 + wave;   // 0..2047
  const int bb = p >> 6, t = p & 63;

  union { uint4 q; unsigned short us[8]; } dv;
  dv.q = *reinterpret_cast<const uint4*>(d1_bf + (bb * 64 + t) * NU + lane * 8);
  float d1f[8], Vf[8];
#pragma unroll
  for (int e = 0; e < 8; ++e) { d1f[e] = bf2f(dv.us[e]); Vf[e] = V[lane * 8 + e]; }

  float sc = 0.f;
  for (int s = 0; s < NS; ++s) {
    union { uint4 q; unsigned short us[8]; } ev;
    ev.q = *reinterpret_cast<const uint4*>(e2_bf + (bb * 64 + s) * NU + lane * 8);
    float part = 0.f;
#pragma unroll
    for (int e = 0; e < 8; ++e) part += tanhfast(d1f[e] + bf2f(ev.us[e])) * Vf[e];
#pragma unroll
    for (int o = 32; o > 0; o >>= 1) part += __shfl_xor(part, o);
    sc = (lane == s) ? part : sc;
  }
  float m = sc;
#pragma unroll
  for (int o = 32; o > 0; o >>= 1) m = fmaxf(m, __shfl_xor(m, o));
  float ex = __expf(sc - m);
  float sum = ex;
#pragma unroll
  for (int o = 32; o > 0; o >>= 1) sum += __shfl_xor(sum, o);
  out[(bb * 64 + lane) * 64 + t] = ex / sum;
}

// ---------------------------------------------------------------------------
extern "C" void kernel_launch(void* const* d_in, const int* in_sizes, int n_in,
                              void* d_out, int out_size, void* d_ws, size_t ws_size,
                              hipStream_t stream)
{
  (void)in_sizes; (void)n_in; (void)out_size;
  const int*   labels = (const int*)  d_in[0];
  const float* enc    = (const float*)d_in[1];
  const float* h0     = (const float*)d_in[2];
  const float* c0     = (const float*)d_in[3];
  const float* Wx     = (const float*)d_in[4];
  const float* Wh     = (const float*)d_in[5];
  const float* bias   = (const float*)d_in[6];
  const float* W1     = (const float*)d_in[7];
  const float* b1     = (const float*)d_in[8];
  const float* W2     = (const float*)d_in[9];
  const float* b2     = (const float*)d_in[10];
  const float* V      = (const float*)d_in[11];
  // d_in[12] = bv: additive scalar on all scores -> softmax-invariant.

  char* ws = (char*)d_ws;
  const size_t OFS_HBUF = 1024;                       // 64KB exchange
  const size_t OFS_DEC  = 1u << 17;                   // 2MB
  const size_t OFS_D1   = OFS_DEC + (2u << 20);       // 2MB
  const size_t OFS_E2   = OFS_D1  + (2u << 20);       // 2MB
  if (ws_size < OFS_E2 + (2u << 20)) return;          // ~8.4MB needed

  u32* flags = (u32*)(ws);
  u32* hbuf  = (u32*)(ws + OFS_HBUF);
  u32* dec_u = (u32*)(ws + OFS_DEC);
  unsigned short* d1_bf = (unsigned short*)(ws + OFS_D1);
  unsigned short* e2_bf = (unsigned short*)(ws + OFS_E2);
  float* out = (float*)d_out;

  hipMemsetAsync(flags, 0, 256, stream);
  lstm_kernel<<<dim3(64), dim3(256), 0, stream>>>(labels, h0, c0, Wx, Wh, bias,
                                                  enc, W2, b2,
                                                  hbuf, dec_u, flags, e2_bf);
  proj_kernel<<<dim3(256), dim3(256), 0, stream>>>(dec_u, W1, b1, d1_bf);
  score_kernel<<<dim3(512), dim3(256), 0, stream>>>(d1_bf, e2_bf, V, out);
}